// Round 8
// baseline (699.572 us; speedup 1.0000x reference)
//
#include <hip/hip_runtime.h>
#include <hip/hip_bf16.h>
#include <math.h>

#define NN 20000
#define EE 320000
#define NFD 74
#define EFD 12

__device__ __forceinline__ float leakyf(float x) { return x > 0.f ? x : 0.01f * x; }
__device__ __forceinline__ float b2f(unsigned short u) {
    union { unsigned int i; float f; } x; x.i = ((unsigned int)u) << 16; return x.f;
}
__device__ __forceinline__ unsigned short f2b(float f) {
    __hip_bfloat16 h = __float2bfloat16(f);
    return *(unsigned short*)&h;
}

// ================= batched 128x128-tile fp32 GEMM (8x8/thread) =================
struct GJob {
    const float* A; const float* B; const float* bias; float* C; const int* cnt;
    int a_off; int c_off; unsigned short* ph;   // ph: optional bf16 copy of cols>=384
};

// ACT: 0 none, 2 elu with empty-node guard (cnt[gr]>0), 3 leaky-if-col<split
template <int ACT>
__global__ __launch_bounds__(256) void gemm256(
    GJob j0, GJob j1, GJob j2,
    int lda, int ldb, int ldc, int nrows, int K, int M, int split)
{
    GJob jb = (blockIdx.y == 0) ? j0 : ((blockIdx.y == 1) ? j1 : j2);
    const int tiles_m = (M + 127) >> 7;
    const int tn = blockIdx.x / tiles_m;
    const int tm = blockIdx.x % tiles_m;
    const int n0 = tn << 7, m0 = tm << 7;
    __shared__ __align__(16) float As[32][128];
    __shared__ __align__(16) float Bs[32][132];
    const int tid = threadIdx.x;
    const int sr = tid >> 1;
    const int sk = (tid & 1) * 16;
    const int br = tid >> 3;
    const int bc = (tid & 7) * 16;
    const int rr = (tid & 15) * 4;
    const int cc = (tid >> 4) * 4;
    const bool al = ((lda | jb.a_off) & 3) == 0;
    float acc[8][8];
#pragma unroll
    for (int i = 0; i < 8; i++)
#pragma unroll
        for (int j = 0; j < 8; j++) acc[i][j] = 0.f;

    for (int k0 = 0; k0 < K; k0 += 32) {
        {
            const int grow = n0 + sr;
            const bool rok = grow < nrows;
            const float* Ap = jb.A + (size_t)grow * lda + jb.a_off + k0 + sk;
#pragma unroll
            for (int r = 0; r < 16; r += 4) {
                int gj = k0 + sk + r;
                float4 v;
                if (rok && al && gj + 3 < K) {
                    v = *(const float4*)(Ap + r);
                } else {
                    v.x = (rok && gj     < K) ? Ap[r]     : 0.f;
                    v.y = (rok && gj + 1 < K) ? Ap[r + 1] : 0.f;
                    v.z = (rok && gj + 2 < K) ? Ap[r + 2] : 0.f;
                    v.w = (rok && gj + 3 < K) ? Ap[r + 3] : 0.f;
                }
                As[sk + r][sr] = v.x; As[sk + r + 1][sr] = v.y;
                As[sk + r + 2][sr] = v.z; As[sk + r + 3][sr] = v.w;
            }
        }
        {
            const int gj = k0 + br;
            const bool jok = gj < K;
            const float* Bp = jb.B + (size_t)gj * ldb + m0 + bc;
#pragma unroll
            for (int r = 0; r < 16; r += 4) {
                float4 v = make_float4(0.f, 0.f, 0.f, 0.f);
                if (jok) v = *(const float4*)(Bp + r);
                *(float4*)&Bs[br][bc + r] = v;
            }
        }
        __syncthreads();
#pragma unroll
        for (int kk = 0; kk < 32; kk++) {
            float4 a0 = *(const float4*)&As[kk][rr];
            float4 a1 = *(const float4*)&As[kk][rr + 64];
            float4 b0 = *(const float4*)&Bs[kk][cc];
            float4 b1 = *(const float4*)&Bs[kk][cc + 64];
            float av[8] = {a0.x, a0.y, a0.z, a0.w, a1.x, a1.y, a1.z, a1.w};
            float bv[8] = {b0.x, b0.y, b0.z, b0.w, b1.x, b1.y, b1.z, b1.w};
#pragma unroll
            for (int i = 0; i < 8; i++)
#pragma unroll
                for (int j = 0; j < 8; j++)
                    acc[i][j] += av[i] * bv[j];
        }
        __syncthreads();
    }
#pragma unroll
    for (int h = 0; h < 2; h++)
#pragma unroll
    for (int i = 0; i < 4; i++) {
        const int gr = n0 + rr + h * 64 + i;
        if (gr >= nrows) continue;
        bool pos = true;
        if (ACT == 2) pos = jb.cnt[gr] > 0;
        float* Crow = jb.C + (size_t)gr * ldc + jb.c_off;
#pragma unroll
        for (int g2 = 0; g2 < 2; g2++) {
            const int gc = m0 + cc + g2 * 64;
            if (gc >= M) continue;
            float4 v;
            float* a = &acc[h * 4 + i][g2 * 4];
            v.x = a[0] + jb.bias[gc + 0];
            v.y = a[1] + jb.bias[gc + 1];
            v.z = a[2] + jb.bias[gc + 2];
            v.w = a[3] + jb.bias[gc + 3];
            if (ACT == 2) {
                v.x = pos ? (v.x > 0.f ? v.x : (__expf(v.x) - 1.f)) : 0.f;
                v.y = pos ? (v.y > 0.f ? v.y : (__expf(v.y) - 1.f)) : 0.f;
                v.z = pos ? (v.z > 0.f ? v.z : (__expf(v.z) - 1.f)) : 0.f;
                v.w = pos ? (v.w > 0.f ? v.w : (__expf(v.w) - 1.f)) : 0.f;
            }
            if (ACT == 3) {
                const int gcc = jb.c_off + gc;
                if (gcc + 0 < split) v.x = leakyf(v.x);
                if (gcc + 1 < split) v.y = leakyf(v.y);
                if (gcc + 2 < split) v.z = leakyf(v.z);
                if (gcc + 3 < split) v.w = leakyf(v.w);
                if (jb.ph && gcc >= split) {
                    ushort4 hb;
                    hb.x = f2b(v.x); hb.y = f2b(v.y); hb.z = f2b(v.z); hb.w = f2b(v.w);
                    *(ushort4*)(jb.ph + (size_t)gr * 384 + (gcc - split)) = hb;
                }
            }
            *(float4*)(Crow + gc) = v;
        }
    }
}

// ================= weight packing (PK padded to K=80) =================
__global__ void k_pack(
    const float* __restrict__ pn0, const float* __restrict__ pn1, const float* __restrict__ pn2,
    const float* __restrict__ pb0, const float* __restrict__ pb1, const float* __restrict__ pb2,
    const float* __restrict__ pe0, const float* __restrict__ pe1, const float* __restrict__ pe2,
    const float* __restrict__ qb0, const float* __restrict__ qb1, const float* __restrict__ qb2,
    const float* __restrict__ wih, const float* __restrict__ whh,
    float* __restrict__ PK, float* __restrict__ PB, float* __restrict__ WG, float* __restrict__ Z512)
{
    int idx = blockIdx.x * 256 + threadIdx.x;
    const float* pnw[3] = {pn0, pn1, pn2};
    const float* pew[3] = {pe0, pe1, pe2};
    const float* pnb[3] = {pb0, pb1, pb2};
    const float* peb[3] = {qb0, qb1, qb2};
    if (idx < 131072) {
        int r = idx >> 9, c = idx & 511;
        float v;
        if (r < 128) v = (c < 384) ? wih[r * 384 + c] : 0.f;
        else {
            int rr = r - 128;
            if (c < 256) v = whh[rr * 384 + c];
            else if (c < 384) v = 0.f;
            else v = whh[rr * 384 + (c - 128)];
        }
        WG[idx] = v;
    } else if (idx < 131072 + 61440) {
        int t = idx - 131072;
        int r = t / 768, c = t - r * 768;
        int k = (c >> 7) % 3, cc = c & 127;
        PK[t] = (r < NFD) ? ((c < 384) ? pnw[k][r * 128 + cc] : pew[k][r * 128 + cc]) : 0.f;
    } else if (idx < 131072 + 61440 + 768) {
        int c = idx - (131072 + 61440);
        int k = (c >> 7) % 3, cc = c & 127;
        PB[c] = (c < 384) ? pnb[k][cc] : peb[k][cc];
    } else if (idx < 131072 + 61440 + 768 + 512) {
        Z512[idx - (131072 + 61440 + 768)] = 0.f;
    }
}

// nf [N,74] -> PA [N,80] zero-padded
__global__ void k_prep(const float* __restrict__ nf, float* __restrict__ PA)
{
    int idx = blockIdx.x * 256 + threadIdx.x;
    if (idx < NN * 80) {
        int n = idx / 80, c = idx - n * 80;
        PA[idx] = (c < NFD) ? nf[n * NFD + c] : 0.f;
    }
}

// ================= CSR build (disjoint ranges, no scan) =================
__global__ void k_count(const int* __restrict__ dst, int* __restrict__ cnt)
{
    int e = blockIdx.x * 256 + threadIdx.x;
    if (e < EE) atomicAdd(&cnt[dst[e]], 1);
}

__global__ void k_off(const int* __restrict__ cnt, int* __restrict__ offs,
                      int* __restrict__ cur, int* __restrict__ total)
{
    int n = blockIdx.x * 256 + threadIdx.x;
    if (n < NN) {
        int c = cnt[n];
        int o = atomicAdd(total, c);
        offs[n] = o;
        cur[n] = o;
    }
}

__global__ void k_fill(const int* __restrict__ dst, const int* __restrict__ src,
                       const float* __restrict__ ef,
                       int* __restrict__ cur, int* __restrict__ csr_src,
                       float* __restrict__ EFC)
{
    int e = blockIdx.x * 256 + threadIdx.x;
    if (e < EE) {
        int p = atomicAdd(&cur[dst[e]], 1);
        csr_src[p] = src[e];
        const float4* s = (const float4*)(ef + (size_t)e * 12);
        float4* d = (float4*)(EFC + (size_t)p * 12);
        float4 v0 = s[0], v1 = s[1], v2 = s[2];
        d[0] = v0; d[1] = v1; d[2] = v2;
    }
}

// ================= fused edge pipeline =================
// block = 128 threads = 2 waves, both for the SAME (node, branch)=blockIdx.x/(.x%3).
// wave h handles edge slots {h*4+er + 8m}; partials combined via LDS.
// lane = er(4 slots) x cg(16 ch-groups of 8 ch). Pn gathered in bf16 from PH.
__global__ __launch_bounds__(128) void k_fused(
    const float* __restrict__ HP,          // [N,768]: hv | Pn(fp32)
    const unsigned short* __restrict__ PH, // [N,384] bf16 Pn
    const float* __restrict__ EFC,         // CSR-ordered edge feats [E,12]
    const float* __restrict__ pw0, const float* __restrict__ pw1, const float* __restrict__ pw2,
    const float* __restrict__ v0, const float* __restrict__ v1, const float* __restrict__ v2,
    const float* __restrict__ b20, const float* __restrict__ b21, const float* __restrict__ b22,
    const int* __restrict__ csr_src,
    const int* __restrict__ offs, const int* __restrict__ cnt,
    float* __restrict__ AX)
{
    const int n = blockIdx.x / 3;
    const int k = blockIdx.x - n * 3;
    const int h = threadIdx.x >> 6;
    const int lane = threadIdx.x & 63;
    const int er = lane >> 4, cg = lane & 15;
    const int c4 = cg * 4;
    const float* pw = (k == 0) ? pw0 : (k == 1) ? pw1 : pw2;
    const float* vv = (k == 0) ? v0 : (k == 1) ? v1 : v2;
    const float b2 = ((k == 0) ? b20 : (k == 1) ? b21 : b22)[0];
    const float* We = pw + NFD * 128;

    __shared__ float sA[2][16][8];
    __shared__ float sS[2];

    const int o0 = offs[n];
    const int deg = cnt[n];

    float4 wb0 = *(const float4*)(vv + 128 + c4);
    float4 wb1 = *(const float4*)(vv + 128 + 64 + c4);

    // qa = hv_k[n] . w2a
    float qa;
    {
        float4 wa0 = *(const float4*)(vv + c4);
        float4 wa1 = *(const float4*)(vv + 64 + c4);
        const float* hr = HP + (size_t)n * 768 + k * 128;
        float4 h0 = *(const float4*)(hr + c4);
        float4 h1 = *(const float4*)(hr + 64 + c4);
        qa = h0.x * wa0.x + h0.y * wa0.y + h0.z * wa0.z + h0.w * wa0.w
           + h1.x * wa1.x + h1.y * wa1.y + h1.z * wa1.z + h1.w * wa1.w;
#pragma unroll
        for (int d = 1; d < 16; d <<= 1) qa += __shfl_xor(qa, d, 64);
    }

    float4 a0 = make_float4(0.f, 0.f, 0.f, 0.f);
    float4 a1 = make_float4(0.f, 0.f, 0.f, 0.f);
    float s = 0.f;

    const int base0 = h * 4;
    if (base0 < deg) {
        // prologue prefetch
        int p0 = base0 + er;
        int q = o0 + (p0 < deg ? p0 : 0);
        int sn_c = csr_src[q];
        const float4* ep = (const float4*)(EFC + (size_t)q * 12);
        float4 ec0 = ep[0], ec1 = ep[1], ec2 = ep[2];

        for (int base = base0; base < deg; base += 8) {
            const bool on = (base + er) < deg;
            // issue bf16 Pn gather for current slot
            const unsigned short* pr = PH + (size_t)sn_c * 384 + k * 128;
            ushort4 pb0 = *(const ushort4*)(pr + c4);
            ushort4 pb1 = *(const ushort4*)(pr + 64 + c4);
            // prefetch next slot's sn/ef
            int bn = base + 8;
            int sn_n = sn_c;
            float4 en0 = ec0, en1 = ec1, en2 = ec2;
            if (bn < deg) {
                int pp = bn + er;
                int qn = o0 + (pp < deg ? pp : 0);
                sn_n = csr_src[qn];
                const float4* epn = (const float4*)(EFC + (size_t)qn * 12);
                en0 = epn[0]; en1 = epn[1]; en2 = epn[2];
            }
            // x = sum_j ef_j * W_j (weights via L1)
            float ef[12] = {ec0.x, ec0.y, ec0.z, ec0.w, ec1.x, ec1.y, ec1.z, ec1.w,
                            ec2.x, ec2.y, ec2.z, ec2.w};
            float4 x0 = make_float4(0.f, 0.f, 0.f, 0.f);
            float4 x1 = make_float4(0.f, 0.f, 0.f, 0.f);
#pragma unroll
            for (int j = 0; j < 12; j++) {
                float e = ef[j];
                float4 w0 = *(const float4*)(We + j * 128 + c4);
                float4 w1 = *(const float4*)(We + j * 128 + 64 + c4);
                x0.x += e * w0.x; x0.y += e * w0.y; x0.z += e * w0.z; x0.w += e * w0.w;
                x1.x += e * w1.x; x1.y += e * w1.y; x1.z += e * w1.z; x1.w += e * w1.w;
            }
            // add gathered Pn (bf16->f32), activation
            x0.x = leakyf(x0.x + b2f(pb0.x)); x0.y = leakyf(x0.y + b2f(pb0.y));
            x0.z = leakyf(x0.z + b2f(pb0.z)); x0.w = leakyf(x0.w + b2f(pb0.w));
            x1.x = leakyf(x1.x + b2f(pb1.x)); x1.y = leakyf(x1.y + b2f(pb1.y));
            x1.z = leakyf(x1.z + b2f(pb1.z)); x1.w = leakyf(x1.w + b2f(pb1.w));
            float dd = x0.x * wb0.x + x0.y * wb0.y + x0.z * wb0.z + x0.w * wb0.w
                     + x1.x * wb1.x + x1.y * wb1.y + x1.z * wb1.z + x1.w * wb1.w;
#pragma unroll
            for (int d = 1; d < 16; d <<= 1) dd += __shfl_xor(dd, d, 64);
            float ex = on ? __expf(leakyf(qa + dd + b2)) : 0.f;
            a0.x += ex * x0.x; a0.y += ex * x0.y; a0.z += ex * x0.z; a0.w += ex * x0.w;
            a1.x += ex * x1.x; a1.y += ex * x1.y; a1.z += ex * x1.z; a1.w += ex * x1.w;
            s += ex;
            sn_c = sn_n; ec0 = en0; ec1 = en1; ec2 = en2;
        }
    }
    // in-wave reduce over edge slots
#pragma unroll
    for (int d = 16; d < 64; d <<= 1) {
        a0.x += __shfl_xor(a0.x, d, 64); a0.y += __shfl_xor(a0.y, d, 64);
        a0.z += __shfl_xor(a0.z, d, 64); a0.w += __shfl_xor(a0.w, d, 64);
        a1.x += __shfl_xor(a1.x, d, 64); a1.y += __shfl_xor(a1.y, d, 64);
        a1.z += __shfl_xor(a1.z, d, 64); a1.w += __shfl_xor(a1.w, d, 64);
        s += __shfl_xor(s, d, 64);
    }
    // cross-wave combine
    if (er == 0) {
        sA[h][cg][0] = a0.x; sA[h][cg][1] = a0.y; sA[h][cg][2] = a0.z; sA[h][cg][3] = a0.w;
        sA[h][cg][4] = a1.x; sA[h][cg][5] = a1.y; sA[h][cg][6] = a1.z; sA[h][cg][7] = a1.w;
    }
    if (lane == 0) sS[h] = s;
    __syncthreads();
    if (h == 0 && er == 0) {
        float* arow = AX + (size_t)n * 384 + k * 128;
        if (deg > 0) {
            float st = s + sS[1];
            float inv = 1.f / st;
            a0.x = (a0.x + sA[1][cg][0]) * inv; a0.y = (a0.y + sA[1][cg][1]) * inv;
            a0.z = (a0.z + sA[1][cg][2]) * inv; a0.w = (a0.w + sA[1][cg][3]) * inv;
            a1.x = (a1.x + sA[1][cg][4]) * inv; a1.y = (a1.y + sA[1][cg][5]) * inv;
            a1.z = (a1.z + sA[1][cg][6]) * inv; a1.w = (a1.w + sA[1][cg][7]) * inv;
        } else {
            a0 = make_float4(0.f, 0.f, 0.f, 0.f);
            a1 = make_float4(0.f, 0.f, 0.f, 0.f);
        }
        *(float4*)(arow + c4) = a0;
        *(float4*)(arow + 64 + c4) = a1;
    }
}

// ================= fused GRU gates + relu =================
__global__ void k_gru2(const float* __restrict__ G, const float* __restrict__ X,
                       const float* __restrict__ bih, const float* __restrict__ bhh,
                       float* __restrict__ out)
{
    int idx = blockIdx.x * 256 + threadIdx.x;
    if (idx >= NN * 128) return;
    int n = idx >> 7, c = idx & 127;
    const float* g = G + (size_t)n * 512;
    float r = 1.f / (1.f + __expf(-(g[c] + bih[c] + bhh[c])));
    float z = 1.f / (1.f + __expf(-(g[128 + c] + bih[128 + c] + bhh[128 + c])));
    float nv = tanhf(g[256 + c] + bih[256 + c] + r * (g[384 + c] + bhh[256 + c]));
    float h = X[(size_t)n * 256 + 128 + c];
    float v = (1.f - z) * nv + z * h;
    out[idx] = v > 0.f ? v : 0.f;
}

extern "C" void kernel_launch(void* const* d_in, const int* in_sizes, int n_in,
                              void* d_out, int out_size, void* d_ws, size_t ws_size,
                              hipStream_t stream)
{
    const float* nf = (const float*)d_in[0];
    const float* ef = (const float*)d_in[1];
    const float *pn_w[3], *pn_b[3], *pe1_w[3], *pe1_b[3], *pe2_w[3], *pe2_b[3], *et_w[3], *et_b[3];
    for (int k = 0; k < 3; k++) {
        int b = 2 + k * 8;
        pn_w[k] = (const float*)d_in[b + 0]; pn_b[k] = (const float*)d_in[b + 1];
        pe1_w[k] = (const float*)d_in[b + 2]; pe1_b[k] = (const float*)d_in[b + 3];
        pe2_w[k] = (const float*)d_in[b + 4]; pe2_b[k] = (const float*)d_in[b + 5];
        et_w[k] = (const float*)d_in[b + 6]; et_b[k] = (const float*)d_in[b + 7];
    }
    const float* mca_w = (const float*)d_in[26]; const float* mca_b = (const float*)d_in[27];
    const float* mcn_w = (const float*)d_in[28]; const float* mcn_b = (const float*)d_in[29];
    const float* wih = (const float*)d_in[30]; const float* whh = (const float*)d_in[31];
    const float* bih = (const float*)d_in[32]; const float* bhh = (const float*)d_in[33];
    const int* src = (const int*)d_in[34];
    const int* dst = (const int*)d_in[35];

    float* W = (float*)d_ws;
    size_t o = 0;
    float* HP = W + o;   o += (size_t)NN * 768;   // hv | Pn->CTX; reused as G [N,512]
    float* AX = W + o;   o += (size_t)NN * 384;   // weighted sums; reused as X [N,256]
    float* EFC = W + o;  o += (size_t)EE * 12;    // CSR edge feats; head aliased as PA [N,80]
    float* PK = W + o;   o += 80 * 768;
    float* PB = W + o;   o += 768;
    float* WG = W + o;   o += 256 * 512;
    float* Z512 = W + o; o += 512;
    unsigned short* PHu = (unsigned short*)(W + o); o += (size_t)NN * 192;  // [N,384] bf16
    int* cnt = (int*)(W + o);
    int* total = cnt + NN;
    int* offs = total + 1;
    int* cur = offs + NN;
    int* csr_src = cur + NN;
    size_t need = o * 4 + (size_t)(NN * 3 + 1 + EE) * 4;
    if (ws_size < need) return;  // fail loudly (out stays poisoned)

    float* PA = EFC;  // [N,80] padded nf; dead before k_fill overwrites EFC
    float* Xb = AX;   // [N,256]
    float* Gb = HP;   // [N,512]

    hipMemsetAsync(cnt, 0, (NN + 1) * sizeof(int), stream);  // cnt + total

    dim3 blk(256);
    k_pack<<<757, blk, 0, stream>>>(
        pn_w[0], pn_w[1], pn_w[2], pn_b[0], pn_b[1], pn_b[2],
        pe1_w[0], pe1_w[1], pe1_w[2], pe1_b[0], pe1_b[1], pe1_b[2],
        wih, whh, PK, PB, WG, Z512);
    k_prep<<<(NN * 80 + 255) / 256, blk, 0, stream>>>(nf, PA);

    const int rt = (NN + 127) / 128;   // 157

    // HP = [leaky(PA@pnw+b) | PA@pe1w+b]; also emit bf16 Pn copy
    {
        GJob j = {PA, PK, PB, HP, nullptr, 0, 0, PHu};
        gemm256<3><<<dim3(rt * 6, 1), blk, 0, stream>>>(j, j, j, 80, 768, 768, NN, 80, 768, 384);
    }

    k_count<<<(EE + 255) / 256, blk, 0, stream>>>(dst, cnt);
    k_off<<<(NN + 255) / 256, blk, 0, stream>>>(cnt, offs, cur, total);
    k_fill<<<(EE + 255) / 256, blk, 0, stream>>>(dst, src, ef, cur, csr_src, EFC);

    // fused: qa + he1k + logits + softmax + weighted aggregation (2 waves/node-branch)
    k_fused<<<dim3(NN * 3), dim3(128), 0, stream>>>(HP, PHu, EFC,
        pe1_w[0], pe1_w[1], pe1_w[2], pe2_w[0], pe2_w[1], pe2_w[2],
        pe2_b[0], pe2_b[1], pe2_b[2], csr_src, offs, cnt, AX);

    // ctx_k = elu(AX_k @ et_w + b) -> HP cols 384.. (batched over k, empty-node guard)
    {
        GJob j0 = {AX, et_w[0], et_b[0], HP, cnt, 0 * 128, 384 + 0 * 128, nullptr};
        GJob j1 = {AX, et_w[1], et_b[1], HP, cnt, 1 * 128, 384 + 1 * 128, nullptr};
        GJob j2 = {AX, et_w[2], et_b[2], HP, cnt, 2 * 128, 384 + 2 * 128, nullptr};
        gemm256<2><<<dim3(rt, 3), blk, 0, stream>>>(j0, j1, j2, 384, 128, 768, NN, 128, 128, 0);
    }
    // X[:,0:128] = ctx@mca_w+b ; X[:,128:256] = hv@mcn_w+b (batched)
    {
        GJob j0 = {HP, mca_w, mca_b, Xb, nullptr, 384, 0, nullptr};
        GJob j1 = {HP, mcn_w, mcn_b, Xb, nullptr, 0, 128, nullptr};
        gemm256<0><<<dim3(rt, 2), blk, 0, stream>>>(j0, j1, j1, 768, 128, 256, NN, 384, 128, 0);
    }
    // G = X @ WG  (r|z|in|hn)
    {
        GJob j = {Xb, WG, Z512, Gb, nullptr, 0, 0, nullptr};
        gemm256<0><<<dim3(rt * 4, 1), blk, 0, stream>>>(j, j, j, 256, 512, 512, NN, 256, 512, 0);
    }

    k_gru2<<<(NN * 128 + 255) / 256, blk, 0, stream>>>(Gb, Xb, bih, bhh, (float*)d_out);
}

// Round 10
// 529.561 us; speedup vs baseline: 1.3210x; 1.3210x over previous
//
#include <hip/hip_runtime.h>
#include <hip/hip_bf16.h>
#include <math.h>

#define NN 20000
#define EE 320000
#define NFD 74
#define EFD 12

__device__ __forceinline__ float leakyf(float x) { return x > 0.f ? x : 0.01f * x; }
__device__ __forceinline__ float b2f(unsigned short u) {
    union { unsigned int i; float f; } x; x.i = ((unsigned int)u) << 16; return x.f;
}
__device__ __forceinline__ unsigned short f2b(float f) {
    __hip_bfloat16 h = __float2bfloat16(f);
    return *(unsigned short*)&h;
}

typedef __bf16 v8bf __attribute__((ext_vector_type(8)));
typedef float v4f __attribute__((ext_vector_type(4)));
typedef unsigned short us8v __attribute__((ext_vector_type(8)));
union FragU { v8bf v; ushort4 h[2]; };

// ================= batched MFMA bf16 GEMM, 128x128 tile, 4 waves ==============
struct GJob {
    const float* A; const float* B; const float* bias; float* C; const int* cnt;
    int a_off; int c_off; unsigned short* ph;   // ph: optional bf16 copy of cols>=split
};

// ACT: 0 none, 2 elu with empty-node guard (cnt[gr]>0), 3 leaky-if-col<split (+ph)
// Requires: M multiple of 128, K multiple of 16, 16B-aligned A rows (lda,a_off mult of 4).
template <int ACT>
__global__ __launch_bounds__(256) void gemm_mfma(
    GJob j0, GJob j1, GJob j2,
    int lda, int ldb, int ldc, int nrows, int K, int M, int split)
{
    GJob jb = (blockIdx.y == 0) ? j0 : ((blockIdx.y == 1) ? j1 : j2);
    const int tiles_m = M >> 7;
    const int tn = blockIdx.x / tiles_m;
    const int tm = blockIdx.x % tiles_m;
    const int n0 = tn << 7, m0 = tm << 7;
    __shared__ __align__(16) unsigned short As[128][40];   // [row][k] bf16, padded
    __shared__ __align__(16) unsigned short Bt[128][40];   // [col][k] bf16, padded
    const int tid = threadIdx.x;
    const int w = tid >> 6, l = tid & 63;
    const int wr = (w >> 1) * 64, wc = (w & 1) * 64;   // wave tile origin in block
    const int fr = l & 15, fg = l >> 4;                // fragment index / 16-lane group

    v4f acc[4][4];
#pragma unroll
    for (int ri = 0; ri < 4; ri++)
#pragma unroll
        for (int ci = 0; ci < 4; ci++) {
            acc[ri][ci][0] = 0.f; acc[ri][ci][1] = 0.f;
            acc[ri][ci][2] = 0.f; acc[ri][ci][3] = 0.f;
        }

    for (int k0 = 0; k0 < K; k0 += 32) {
        // stage A: row = tid>>1 (0..127), ks = (tid&1)*16
        {
            const int row = tid >> 1, ks = (tid & 1) << 4;
            const int grow = n0 + row;
            const bool rok = grow < nrows;
            const float* Ap = jb.A + (size_t)grow * lda + jb.a_off + k0 + ks;
            unsigned short* dstp = &As[row][ks];
#pragma unroll
            for (int r = 0; r < 16; r += 4) {
                const int gk = k0 + ks + r;
                float4 v = make_float4(0.f, 0.f, 0.f, 0.f);
                if (rok && gk + 3 < K) v = *(const float4*)(Ap + r);
                dstp[r + 0] = f2b(v.x); dstp[r + 1] = f2b(v.y);
                dstp[r + 2] = f2b(v.z); dstp[r + 3] = f2b(v.w);
            }
        }
        // stage B transposed: kk = tid>>3 (0..31), cb = (tid&7)*16
        {
            const int kk = tid >> 3, cb = (tid & 7) << 4;
            const int gk = k0 + kk;
            const bool kok = gk < K;
            const float* Bp = jb.B + (size_t)gk * ldb + m0 + cb;
#pragma unroll
            for (int r = 0; r < 4; r++) {
                float4 v = make_float4(0.f, 0.f, 0.f, 0.f);
                if (kok) v = *(const float4*)(Bp + r * 4);
                const int c = cb + r * 4;
                Bt[c + 0][kk] = f2b(v.x); Bt[c + 1][kk] = f2b(v.y);
                Bt[c + 2][kk] = f2b(v.z); Bt[c + 3][kk] = f2b(v.w);
            }
        }
        __syncthreads();
        // fragments: elem 0-3 <- k = fg*4+i (first 16-block), elem 4-7 <- k = 16+fg*4+i
        FragU fa[4], fb[4];
#pragma unroll
        for (int ri = 0; ri < 4; ri++) {
            const unsigned short* ap = &As[wr + ri * 16 + fr][0];
            fa[ri].h[0] = *(const ushort4*)(ap + fg * 4);
            fa[ri].h[1] = *(const ushort4*)(ap + 16 + fg * 4);
        }
#pragma unroll
        for (int ci = 0; ci < 4; ci++) {
            const unsigned short* bp = &Bt[wc + ci * 16 + fr][0];
            fb[ci].h[0] = *(const ushort4*)(bp + fg * 4);
            fb[ci].h[1] = *(const ushort4*)(bp + 16 + fg * 4);
        }
#pragma unroll
        for (int ri = 0; ri < 4; ri++)
#pragma unroll
            for (int ci = 0; ci < 4; ci++)
                acc[ri][ci] = __builtin_amdgcn_mfma_f32_16x16x32_bf16(
                    fa[ri].v, fb[ci].v, acc[ri][ci], 0, 0, 0);
        __syncthreads();
    }
    // epilogue: C/D layout col = lane&15, row = (lane>>4)*4 + j  [HW-verified]
#pragma unroll
    for (int ci = 0; ci < 4; ci++) {
        const int gcol = m0 + wc + ci * 16 + fr;
        const float bi = jb.bias[gcol];
        const int gcc = jb.c_off + gcol;
#pragma unroll
        for (int ri = 0; ri < 4; ri++) {
#pragma unroll
            for (int j = 0; j < 4; j++) {
                const int grow = n0 + wr + ri * 16 + fg * 4 + j;
                if (grow >= nrows) continue;
                float v = acc[ri][ci][j] + bi;
                if (ACT == 2) {
                    bool pos = jb.cnt[grow] > 0;
                    v = pos ? (v > 0.f ? v : (__expf(v) - 1.f)) : 0.f;
                }
                if (ACT == 3) {
                    if (gcc < split) v = leakyf(v);
                    else if (jb.ph) jb.ph[(size_t)grow * 384 + (gcc - split)] = f2b(v);
                }
                jb.C[(size_t)grow * ldc + gcc] = v;
            }
        }
    }
}

// ================= weight packing (PK padded to K=80) =================
__global__ void k_pack(
    const float* __restrict__ pn0, const float* __restrict__ pn1, const float* __restrict__ pn2,
    const float* __restrict__ pb0, const float* __restrict__ pb1, const float* __restrict__ pb2,
    const float* __restrict__ pe0, const float* __restrict__ pe1, const float* __restrict__ pe2,
    const float* __restrict__ qb0, const float* __restrict__ qb1, const float* __restrict__ qb2,
    const float* __restrict__ wih, const float* __restrict__ whh,
    float* __restrict__ PK, float* __restrict__ PB, float* __restrict__ WG, float* __restrict__ Z512)
{
    int idx = blockIdx.x * 256 + threadIdx.x;
    const float* pnw[3] = {pn0, pn1, pn2};
    const float* pew[3] = {pe0, pe1, pe2};
    const float* pnb[3] = {pb0, pb1, pb2};
    const float* peb[3] = {qb0, qb1, qb2};
    if (idx < 131072) {
        int r = idx >> 9, c = idx & 511;
        float v;
        if (r < 128) v = (c < 384) ? wih[r * 384 + c] : 0.f;
        else {
            int rr = r - 128;
            if (c < 256) v = whh[rr * 384 + c];
            else if (c < 384) v = 0.f;
            else v = whh[rr * 384 + (c - 128)];
        }
        WG[idx] = v;
    } else if (idx < 131072 + 61440) {
        int t = idx - 131072;
        int r = t / 768, c = t - r * 768;
        int k = (c >> 7) % 3, cc = c & 127;
        PK[t] = (r < NFD) ? ((c < 384) ? pnw[k][r * 128 + cc] : pew[k][r * 128 + cc]) : 0.f;
    } else if (idx < 131072 + 61440 + 768) {
        int c = idx - (131072 + 61440);
        int k = (c >> 7) % 3, cc = c & 127;
        PB[c] = (c < 384) ? pnb[k][cc] : peb[k][cc];
    } else if (idx < 131072 + 61440 + 768 + 512) {
        Z512[idx - (131072 + 61440 + 768)] = 0.f;
    }
}

// nf [N,74] -> PA [N,80] zero-padded
__global__ void k_prep(const float* __restrict__ nf, float* __restrict__ PA)
{
    int idx = blockIdx.x * 256 + threadIdx.x;
    if (idx < NN * 80) {
        int n = idx / 80, c = idx - n * 80;
        PA[idx] = (c < NFD) ? nf[n * NFD + c] : 0.f;
    }
}

// ================= CSR build (disjoint ranges, no scan) =================
__global__ void k_count(const int* __restrict__ dst, int* __restrict__ cnt)
{
    int e = blockIdx.x * 256 + threadIdx.x;
    if (e < EE) atomicAdd(&cnt[dst[e]], 1);
}

__global__ void k_off(const int* __restrict__ cnt, int* __restrict__ offs,
                      int* __restrict__ cur, int* __restrict__ total)
{
    int n = blockIdx.x * 256 + threadIdx.x;
    if (n < NN) {
        int c = cnt[n];
        int o = atomicAdd(total, c);
        offs[n] = o;
        cur[n] = o;
    }
}

__global__ void k_fill(const int* __restrict__ dst, const int* __restrict__ src,
                       const float* __restrict__ ef,
                       int* __restrict__ cur, int* __restrict__ csr_src,
                       float* __restrict__ EFC)
{
    int e = blockIdx.x * 256 + threadIdx.x;
    if (e < EE) {
        int p = atomicAdd(&cur[dst[e]], 1);
        csr_src[p] = src[e];
        const float4* s = (const float4*)(ef + (size_t)e * 12);
        float4* d = (float4*)(EFC + (size_t)p * 12);
        float4 v0 = s[0], v1 = s[1], v2 = s[2];
        d[0] = v0; d[1] = v1; d[2] = v2;
    }
}

// ================= fused edge pipeline: wave per (node,branch), 2-deep SW pipe ==
// lane = er(4 edge slots) x cg(16 groups of 8 CONTIGUOUS channels).
// Pn gathered as ONE 16B bf16 load; csr_src/ef prefetched 2 iters ahead,
// PH gather 1 iter ahead -> dependent chain fully covered by the j-loop.
__global__ __launch_bounds__(256) void k_fused(
    const float* __restrict__ HP,          // [N,768]: hv | Pn(fp32)
    const unsigned short* __restrict__ PH, // [N,384] bf16 Pn
    const float* __restrict__ EFC,         // CSR-ordered edge feats [E,12]
    const float* __restrict__ pw0, const float* __restrict__ pw1, const float* __restrict__ pw2,
    const float* __restrict__ v0, const float* __restrict__ v1, const float* __restrict__ v2,
    const float* __restrict__ b20, const float* __restrict__ b21, const float* __restrict__ b22,
    const int* __restrict__ csr_src,
    const int* __restrict__ offs, const int* __restrict__ cnt,
    float* __restrict__ AX)
{
    const int wid = blockIdx.x * 4 + (threadIdx.x >> 6);
    const int n = wid / 3;
    const int k = wid - n * 3;
    if (n >= NN) return;
    const int lane = threadIdx.x & 63;
    const int er = lane >> 4, cg = lane & 15;
    const int c8 = cg * 8;
    const float* pw = (k == 0) ? pw0 : (k == 1) ? pw1 : pw2;
    const float* vv = (k == 0) ? v0 : (k == 1) ? v1 : v2;
    const float b2 = ((k == 0) ? b20 : (k == 1) ? b21 : b22)[0];
    const float* We = pw + NFD * 128;

    const int o0 = offs[n];
    const int deg = cnt[n];
    float* arow = AX + (size_t)n * 384 + k * 128;
    if (deg == 0) {
        if (er == 0) {
            *(float4*)(arow + c8) = make_float4(0.f, 0.f, 0.f, 0.f);
            *(float4*)(arow + c8 + 4) = make_float4(0.f, 0.f, 0.f, 0.f);
        }
        return;
    }

    float4 wb0 = *(const float4*)(vv + 128 + c8);
    float4 wb1 = *(const float4*)(vv + 128 + c8 + 4);

    // qa = hv_k[n] . w2a
    float qa;
    {
        float4 wa0 = *(const float4*)(vv + c8);
        float4 wa1 = *(const float4*)(vv + c8 + 4);
        const float* hr = HP + (size_t)n * 768 + k * 128;
        float4 h0 = *(const float4*)(hr + c8);
        float4 h1 = *(const float4*)(hr + c8 + 4);
        qa = h0.x * wa0.x + h0.y * wa0.y + h0.z * wa0.z + h0.w * wa0.w
           + h1.x * wa1.x + h1.y * wa1.y + h1.z * wa1.z + h1.w * wa1.w;
#pragma unroll
        for (int d = 1; d < 16; d <<= 1) qa += __shfl_xor(qa, d, 64);
    }

    const unsigned short* PHk = PH + (size_t)k * 128 + c8;

    // prologue: stage 0 and stage 1 indices/features, stage-0 gather
    int q0 = o0 + ((er < deg) ? er : (deg - 1));
    int sn0 = csr_src[q0];
    const float4* ep0 = (const float4*)(EFC + (size_t)q0 * 12);
    float4 e00 = ep0[0], e01 = ep0[1], e02 = ep0[2];
    int sn1 = sn0;
    float4 e10 = e00, e11 = e01, e12 = e02;
    if (deg > 4) {
        int p1 = 4 + er;
        int q1 = o0 + ((p1 < deg) ? p1 : (deg - 1));
        sn1 = csr_src[q1];
        const float4* ep1 = (const float4*)(EFC + (size_t)q1 * 12);
        e10 = ep1[0]; e11 = ep1[1]; e12 = ep1[2];
    }
    us8v px0 = *(const us8v*)(PHk + (size_t)sn0 * 384);

    float4 a0 = make_float4(0.f, 0.f, 0.f, 0.f);
    float4 a1 = make_float4(0.f, 0.f, 0.f, 0.f);
    float s = 0.f;

    for (int base = 0; base < deg; base += 4) {
        const bool on = (base + er) < deg;
        // prefetch PH gather for next stage
        us8v px1 = px0;
        if (base + 4 < deg) px1 = *(const us8v*)(PHk + (size_t)sn1 * 384);
        // prefetch sn/ef two stages ahead
        int sn2 = sn1;
        float4 e20 = e10, e21 = e11, e22 = e12;
        if (base + 8 < deg) {
            int p2 = base + 8 + er;
            int q2 = o0 + ((p2 < deg) ? p2 : (deg - 1));
            sn2 = csr_src[q2];
            const float4* ep2 = (const float4*)(EFC + (size_t)q2 * 12);
            e20 = ep2[0]; e21 = ep2[1]; e22 = ep2[2];
        }
        // x = sum_j ef_j * W_j  (weights L1-resident)
        float ef[12] = {e00.x, e00.y, e00.z, e00.w, e01.x, e01.y, e01.z, e01.w,
                        e02.x, e02.y, e02.z, e02.w};
        float4 x0 = make_float4(0.f, 0.f, 0.f, 0.f);
        float4 x1 = make_float4(0.f, 0.f, 0.f, 0.f);
#pragma unroll
        for (int j = 0; j < 12; j++) {
            float e = ef[j];
            float4 w0 = *(const float4*)(We + j * 128 + c8);
            float4 w1 = *(const float4*)(We + j * 128 + c8 + 4);
            x0.x += e * w0.x; x0.y += e * w0.y; x0.z += e * w0.z; x0.w += e * w0.w;
            x1.x += e * w1.x; x1.y += e * w1.y; x1.z += e * w1.z; x1.w += e * w1.w;
        }
        // add gathered Pn (bf16), activation
        x0.x = leakyf(x0.x + b2f(px0[0])); x0.y = leakyf(x0.y + b2f(px0[1]));
        x0.z = leakyf(x0.z + b2f(px0[2])); x0.w = leakyf(x0.w + b2f(px0[3]));
        x1.x = leakyf(x1.x + b2f(px0[4])); x1.y = leakyf(x1.y + b2f(px0[5]));
        x1.z = leakyf(x1.z + b2f(px0[6])); x1.w = leakyf(x1.w + b2f(px0[7]));
        float dd = x0.x * wb0.x + x0.y * wb0.y + x0.z * wb0.z + x0.w * wb0.w
                 + x1.x * wb1.x + x1.y * wb1.y + x1.z * wb1.z + x1.w * wb1.w;
#pragma unroll
        for (int d = 1; d < 16; d <<= 1) dd += __shfl_xor(dd, d, 64);
        float ex = on ? __expf(leakyf(qa + dd + b2)) : 0.f;
        a0.x += ex * x0.x; a0.y += ex * x0.y; a0.z += ex * x0.z; a0.w += ex * x0.w;
        a1.x += ex * x1.x; a1.y += ex * x1.y; a1.z += ex * x1.z; a1.w += ex * x1.w;
        s += ex;
        // rotate pipeline
        px0 = px1; sn1 = sn2;
        e00 = e10; e01 = e11; e02 = e12;
        e10 = e20; e11 = e21; e12 = e22;
    }
#pragma unroll
    for (int d = 16; d < 64; d <<= 1) {
        a0.x += __shfl_xor(a0.x, d, 64); a0.y += __shfl_xor(a0.y, d, 64);
        a0.z += __shfl_xor(a0.z, d, 64); a0.w += __shfl_xor(a0.w, d, 64);
        a1.x += __shfl_xor(a1.x, d, 64); a1.y += __shfl_xor(a1.y, d, 64);
        a1.z += __shfl_xor(a1.z, d, 64); a1.w += __shfl_xor(a1.w, d, 64);
        s += __shfl_xor(s, d, 64);
    }
    if (er == 0) {
        float inv = 1.f / s;
        a0.x *= inv; a0.y *= inv; a0.z *= inv; a0.w *= inv;
        a1.x *= inv; a1.y *= inv; a1.z *= inv; a1.w *= inv;
        *(float4*)(arow + c8) = a0;
        *(float4*)(arow + c8 + 4) = a1;
    }
}

// ================= fused GRU gates + relu =================
__global__ void k_gru2(const float* __restrict__ G, const float* __restrict__ X,
                       const float* __restrict__ bih, const float* __restrict__ bhh,
                       float* __restrict__ out)
{
    int idx = blockIdx.x * 256 + threadIdx.x;
    if (idx >= NN * 128) return;
    int n = idx >> 7, c = idx & 127;
    const float* g = G + (size_t)n * 512;
    float r = 1.f / (1.f + __expf(-(g[c] + bih[c] + bhh[c])));
    float z = 1.f / (1.f + __expf(-(g[128 + c] + bih[128 + c] + bhh[128 + c])));
    float nv = tanhf(g[256 + c] + bih[256 + c] + r * (g[384 + c] + bhh[256 + c]));
    float h = X[(size_t)n * 256 + 128 + c];
    float v = (1.f - z) * nv + z * h;
    out[idx] = v > 0.f ? v : 0.f;
}

extern "C" void kernel_launch(void* const* d_in, const int* in_sizes, int n_in,
                              void* d_out, int out_size, void* d_ws, size_t ws_size,
                              hipStream_t stream)
{
    const float* nf = (const float*)d_in[0];
    const float* ef = (const float*)d_in[1];
    const float *pn_w[3], *pn_b[3], *pe1_w[3], *pe1_b[3], *pe2_w[3], *pe2_b[3], *et_w[3], *et_b[3];
    for (int k = 0; k < 3; k++) {
        int b = 2 + k * 8;
        pn_w[k] = (const float*)d_in[b + 0]; pn_b[k] = (const float*)d_in[b + 1];
        pe1_w[k] = (const float*)d_in[b + 2]; pe1_b[k] = (const float*)d_in[b + 3];
        pe2_w[k] = (const float*)d_in[b + 4]; pe2_b[k] = (const float*)d_in[b + 5];
        et_w[k] = (const float*)d_in[b + 6]; et_b[k] = (const float*)d_in[b + 7];
    }
    const float* mca_w = (const float*)d_in[26]; const float* mca_b = (const float*)d_in[27];
    const float* mcn_w = (const float*)d_in[28]; const float* mcn_b = (const float*)d_in[29];
    const float* wih = (const float*)d_in[30]; const float* whh = (const float*)d_in[31];
    const float* bih = (const float*)d_in[32]; const float* bhh = (const float*)d_in[33];
    const int* src = (const int*)d_in[34];
    const int* dst = (const int*)d_in[35];

    float* W = (float*)d_ws;
    size_t o = 0;
    float* HP = W + o;   o += (size_t)NN * 768;   // hv | Pn->CTX; reused as G [N,512]
    float* AX = W + o;   o += (size_t)NN * 384;   // weighted sums; reused as X [N,256]
    float* EFC = W + o;  o += (size_t)EE * 12;    // CSR edge feats; head aliased as PA [N,80]
    float* PK = W + o;   o += 80 * 768;
    float* PB = W + o;   o += 768;
    float* WG = W + o;   o += 256 * 512;
    float* Z512 = W + o; o += 512;
    unsigned short* PHu = (unsigned short*)(W + o); o += (size_t)NN * 192;  // [N,384] bf16
    int* cnt = (int*)(W + o);
    int* total = cnt + NN;
    int* offs = total + 1;
    int* cur = offs + NN;
    int* csr_src = cur + NN;
    size_t need = o * 4 + (size_t)(NN * 3 + 1 + EE) * 4;
    if (ws_size < need) return;  // fail loudly (out stays poisoned)

    float* PA = EFC;  // [N,80] padded nf; dead before k_fill overwrites EFC
    float* Xb = AX;   // [N,256]
    float* Gb = HP;   // [N,512]

    hipMemsetAsync(cnt, 0, (NN + 1) * sizeof(int), stream);  // cnt + total

    dim3 blk(256);
    k_pack<<<757, blk, 0, stream>>>(
        pn_w[0], pn_w[1], pn_w[2], pn_b[0], pn_b[1], pn_b[2],
        pe1_w[0], pe1_w[1], pe1_w[2], pe1_b[0], pe1_b[1], pe1_b[2],
        wih, whh, PK, PB, WG, Z512);
    k_prep<<<(NN * 80 + 255) / 256, blk, 0, stream>>>(nf, PA);

    const int rt = (NN + 127) / 128;   // 157

    // HP = [leaky(PA@pnw+b) | PA@pe1w+b]; also emit bf16 Pn copy (cols>=384)
    {
        GJob j = {PA, PK, PB, HP, nullptr, 0, 0, PHu};
        gemm_mfma<3><<<dim3(rt * 6, 1), blk, 0, stream>>>(j, j, j, 80, 768, 768, NN, 80, 768, 384);
    }

    k_count<<<(EE + 255) / 256, blk, 0, stream>>>(dst, cnt);
    k_off<<<(NN + 255) / 256, blk, 0, stream>>>(cnt, offs, cur, total);
    k_fill<<<(EE + 255) / 256, blk, 0, stream>>>(dst, src, ef, cur, csr_src, EFC);

    // fused: qa + he1k + logits + softmax + weighted aggregation
    k_fused<<<dim3((NN * 3) / 4), blk, 0, stream>>>(HP, PHu, EFC,
        pe1_w[0], pe1_w[1], pe1_w[2], pe2_w[0], pe2_w[1], pe2_w[2],
        pe2_b[0], pe2_b[1], pe2_b[2], csr_src, offs, cnt, AX);

    // ctx_k = elu(AX_k @ et_w + b) -> HP cols 384.. (batched over k, empty-node guard)
    {
        GJob j0 = {AX, et_w[0], et_b[0], HP, cnt, 0 * 128, 384 + 0 * 128, nullptr};
        GJob j1 = {AX, et_w[1], et_b[1], HP, cnt, 1 * 128, 384 + 1 * 128, nullptr};
        GJob j2 = {AX, et_w[2], et_b[2], HP, cnt, 2 * 128, 384 + 2 * 128, nullptr};
        gemm_mfma<2><<<dim3(rt, 3), blk, 0, stream>>>(j0, j1, j2, 384, 128, 768, NN, 128, 128, 0);
    }
    // X[:,0:128] = ctx@mca_w+b ; X[:,128:256] = hv@mcn_w+b (batched)
    {
        GJob j0 = {HP, mca_w, mca_b, Xb, nullptr, 384, 0, nullptr};
        GJob j1 = {HP, mcn_w, mcn_b, Xb, nullptr, 0, 128, nullptr};
        gemm_mfma<0><<<dim3(rt, 2), blk, 0, stream>>>(j0, j1, j1, 768, 128, 256, NN, 384, 128, 0);
    }
    // G = X @ WG  (r|z|in|hn)
    {
        GJob j = {Xb, WG, Z512, Gb, nullptr, 0, 0, nullptr};
        gemm_mfma<0><<<dim3(rt * 4, 1), blk, 0, stream>>>(j, j, j, 256, 512, 512, NN, 256, 512, 0);
    }

    k_gru2<<<(NN * 128 + 255) / 256, blk, 0, stream>>>(Gb, Xb, bih, bhh, (float*)d_out);
}

// Round 11
// 492.952 us; speedup vs baseline: 1.4191x; 1.0743x over previous
//
#include <hip/hip_runtime.h>
#include <hip/hip_bf16.h>
#include <math.h>

#define NN 20000
#define EE 320000
#define NFD 74
#define EFD 12

__device__ __forceinline__ float leakyf(float x) { return x > 0.f ? x : 0.01f * x; }
__device__ __forceinline__ float b2f(unsigned short u) {
    union { unsigned int i; float f; } x; x.i = ((unsigned int)u) << 16; return x.f;
}
__device__ __forceinline__ unsigned short f2b(float f) {
    __hip_bfloat16 h = __float2bfloat16(f);
    return *(unsigned short*)&h;
}

typedef __bf16 v8bf __attribute__((ext_vector_type(8)));
typedef float v4f __attribute__((ext_vector_type(4)));
typedef unsigned short us8v __attribute__((ext_vector_type(8)));
union FragU { v8bf v; ushort4 h[2]; };

// ======= MFMA bf16 GEMM, 128x128 tile, 4 waves; A row-major bf16, B TRANSPOSED bf16 =======
struct GJob {
    const unsigned short* A;   // [nrows][lda] bf16
    const unsigned short* B;   // [M][K] bf16 (transposed), stride K
    const float* bias;         // [M] fp32
    float* C;                  // optional fp32 out [nrows][ldc]
    unsigned short* Ch;        // optional bf16 out [nrows][ldch]
    const int* cnt;            // ACT==2 guard
    int lda; int a_off; int ldc; int ldch; int c_off;
};

// ACT: 0 none, 2 elu+cnt-guard, 3 leaky-if-col<split
template <int ACT>
__global__ __launch_bounds__(256) void gemm_bf(
    GJob j0, GJob j1, GJob j2, int nrows, int K, int M, int split)
{
    GJob jb = (blockIdx.y == 0) ? j0 : ((blockIdx.y == 1) ? j1 : j2);
    const int tiles_m = M >> 7;
    const int tn = blockIdx.x / tiles_m;
    const int tm = blockIdx.x % tiles_m;
    const int n0 = tn << 7, m0 = tm << 7;
    __shared__ __align__(16) unsigned short As[128][40];
    __shared__ __align__(16) unsigned short Bs[128][40];
    const int tid = threadIdx.x;
    const int w = tid >> 6, l = tid & 63;
    const int wr = (w >> 1) * 64, wc = (w & 1) * 64;
    const int fr = l & 15, fg = l >> 4;

    v4f acc[4][4];
#pragma unroll
    for (int ri = 0; ri < 4; ri++)
#pragma unroll
        for (int ci = 0; ci < 4; ci++) {
            acc[ri][ci][0] = 0.f; acc[ri][ci][1] = 0.f;
            acc[ri][ci][2] = 0.f; acc[ri][ci][3] = 0.f;
        }

    const int row = tid >> 1, half = tid & 1;

    for (int k0 = 0; k0 < K; k0 += 32) {
        const int kb = k0 + half * 16;
        const bool kok = kb < K;   // K is a multiple of 16: chunk fully valid or fully out
        {
            const bool rok = kok && (n0 + row) < nrows;
            const unsigned short* Ap = jb.A + (size_t)(n0 + row) * jb.lda + jb.a_off + kb;
            uint4 v0 = make_uint4(0, 0, 0, 0), v1 = v0;
            if (rok) { v0 = *(const uint4*)Ap; v1 = *(const uint4*)(Ap + 8); }
            *(uint4*)&As[row][half * 16] = v0;
            *(uint4*)&As[row][half * 16 + 8] = v1;
        }
        {
            const unsigned short* Bp = jb.B + (size_t)(m0 + row) * K + kb;
            uint4 v0 = make_uint4(0, 0, 0, 0), v1 = v0;
            if (kok) { v0 = *(const uint4*)Bp; v1 = *(const uint4*)(Bp + 8); }
            *(uint4*)&Bs[row][half * 16] = v0;
            *(uint4*)&Bs[row][half * 16 + 8] = v1;
        }
        __syncthreads();
        FragU fa[4], fb[4];
#pragma unroll
        for (int ri = 0; ri < 4; ri++) {
            const unsigned short* ap = &As[wr + ri * 16 + fr][0];
            fa[ri].h[0] = *(const ushort4*)(ap + fg * 4);
            fa[ri].h[1] = *(const ushort4*)(ap + 16 + fg * 4);
        }
#pragma unroll
        for (int ci = 0; ci < 4; ci++) {
            const unsigned short* bp = &Bs[wc + ci * 16 + fr][0];
            fb[ci].h[0] = *(const ushort4*)(bp + fg * 4);
            fb[ci].h[1] = *(const ushort4*)(bp + 16 + fg * 4);
        }
#pragma unroll
        for (int ri = 0; ri < 4; ri++)
#pragma unroll
            for (int ci = 0; ci < 4; ci++)
                acc[ri][ci] = __builtin_amdgcn_mfma_f32_16x16x32_bf16(
                    fa[ri].v, fb[ci].v, acc[ri][ci], 0, 0, 0);
        __syncthreads();
    }
    // C/D layout: col = lane&15, row = (lane>>4)*4 + j  [HW-verified]
#pragma unroll
    for (int ci = 0; ci < 4; ci++) {
        const int gcol = m0 + wc + ci * 16 + fr;
        const float bi = jb.bias[gcol];
        const int gcc = jb.c_off + gcol;
        const bool lk = (ACT == 3) && (gcc < split);
#pragma unroll
        for (int ri = 0; ri < 4; ri++) {
#pragma unroll
            for (int jj = 0; jj < 4; jj++) {
                const int grow = n0 + wr + ri * 16 + fg * 4 + jj;
                if (grow >= nrows) continue;
                float v = acc[ri][ci][jj] + bi;
                if (ACT == 2) {
                    bool pos = jb.cnt[grow] > 0;
                    v = pos ? (v > 0.f ? v : (__expf(v) - 1.f)) : 0.f;
                }
                if (ACT == 3 && lk) v = leakyf(v);
                if (jb.C)  jb.C[(size_t)grow * jb.ldc + gcc] = v;
                if (jb.Ch) jb.Ch[(size_t)grow * jb.ldch + gcc] = f2b(v);
            }
        }
    }
}

// ================= weight packing: all B matrices TRANSPOSED bf16 =================
#define SZ_PKT 61440
#define SZ_WGT 131072
#define SZ_ETT 49152
#define SZ_MCT 98304
__global__ void k_pack(
    const float* __restrict__ pn0, const float* __restrict__ pn1, const float* __restrict__ pn2,
    const float* __restrict__ pb0, const float* __restrict__ pb1, const float* __restrict__ pb2,
    const float* __restrict__ pe0, const float* __restrict__ pe1, const float* __restrict__ pe2,
    const float* __restrict__ qb0, const float* __restrict__ qb1, const float* __restrict__ qb2,
    const float* __restrict__ wih, const float* __restrict__ whh,
    const float* __restrict__ et0, const float* __restrict__ et1, const float* __restrict__ et2,
    const float* __restrict__ mca, const float* __restrict__ mcn,
    unsigned short* __restrict__ PKt, unsigned short* __restrict__ WGt,
    unsigned short* __restrict__ ETt, unsigned short* __restrict__ MCt,
    float* __restrict__ PB, float* __restrict__ Z512)
{
    int idx = blockIdx.x * 256 + threadIdx.x;
    const float* pnw[3] = {pn0, pn1, pn2};
    const float* pew[3] = {pe0, pe1, pe2};
    const float* pnb[3] = {pb0, pb1, pb2};
    const float* peb[3] = {qb0, qb1, qb2};
    const float* etw[3] = {et0, et1, et2};
    if (idx < SZ_PKT) {                               // PKt [768][80]
        int c = idx / 80, r = idx - c * 80;
        int k = (c >> 7) % 3, cc = c & 127;
        float v = 0.f;
        if (r < NFD) v = (c < 384) ? pnw[k][r * 128 + cc] : pew[k][r * 128 + cc];
        PKt[idx] = f2b(v);
    } else if (idx < SZ_PKT + SZ_WGT) {               // WGt [512][256]
        int t = idx - SZ_PKT;
        int c = t >> 8, r = t & 255;
        float v;
        if (r < 128) v = (c < 384) ? wih[r * 384 + c] : 0.f;
        else {
            int rr = r - 128;
            if (c < 256) v = whh[rr * 384 + c];
            else if (c < 384) v = 0.f;
            else v = whh[rr * 384 + (c - 128)];
        }
        WGt[t] = f2b(v);
    } else if (idx < SZ_PKT + SZ_WGT + SZ_ETT) {      // ETt [3][128][128]
        int t = idx - (SZ_PKT + SZ_WGT);
        int k = t / 16384, rem = t - k * 16384;
        int c = rem >> 7, r = rem & 127;
        ETt[t] = f2b(etw[k][r * 128 + c]);
    } else if (idx < SZ_PKT + SZ_WGT + SZ_ETT + SZ_MCT) {  // MCt [2][128][384]
        int t = idx - (SZ_PKT + SZ_WGT + SZ_ETT);
        int m = t / 49152, rem = t - m * 49152;
        int c = rem / 384, r = rem - c * 384;
        MCt[t] = f2b((m == 0 ? mca : mcn)[r * 128 + c]);
    } else if (idx < SZ_PKT + SZ_WGT + SZ_ETT + SZ_MCT + 768) {
        int c = idx - (SZ_PKT + SZ_WGT + SZ_ETT + SZ_MCT);
        int k = (c >> 7) % 3, cc = c & 127;
        PB[c] = (c < 384) ? pnb[k][cc] : peb[k][cc];
    } else if (idx < SZ_PKT + SZ_WGT + SZ_ETT + SZ_MCT + 768 + 512) {
        Z512[idx - (SZ_PKT + SZ_WGT + SZ_ETT + SZ_MCT + 768)] = 0.f;
    }
}

// nf [N,74] -> PA [N,80] bf16 zero-padded
__global__ void k_prep(const float* __restrict__ nf, unsigned short* __restrict__ PA)
{
    int idx = blockIdx.x * 256 + threadIdx.x;
    if (idx < NN * 80) {
        int n = idx / 80, c = idx - n * 80;
        PA[idx] = f2b((c < NFD) ? nf[n * NFD + c] : 0.f);
    }
}

// ================= CSR build (disjoint ranges, no scan) =================
__global__ void k_count(const int* __restrict__ dst, int* __restrict__ cnt)
{
    int e = blockIdx.x * 256 + threadIdx.x;
    if (e < EE) atomicAdd(&cnt[dst[e]], 1);
}

__global__ void k_off(const int* __restrict__ cnt, int* __restrict__ offs,
                      int* __restrict__ cur, int* __restrict__ total)
{
    int n = blockIdx.x * 256 + threadIdx.x;
    if (n < NN) {
        int c = cnt[n];
        int o = atomicAdd(total, c);
        offs[n] = o;
        cur[n] = o;
    }
}

__global__ void k_fill(const int* __restrict__ dst, const int* __restrict__ src,
                       const float* __restrict__ ef,
                       int* __restrict__ cur, int* __restrict__ csr_src,
                       float* __restrict__ EFC)
{
    int e = blockIdx.x * 256 + threadIdx.x;
    if (e < EE) {
        int p = atomicAdd(&cur[dst[e]], 1);
        csr_src[p] = src[e];
        const float4* s = (const float4*)(ef + (size_t)e * 12);
        float4* d = (float4*)(EFC + (size_t)p * 12);
        float4 v0 = s[0], v1 = s[1], v2 = s[2];
        d[0] = v0; d[1] = v1; d[2] = v2;
    }
}

// ================= fused edge pipeline: BRANCH-MAJOR wave per (node,branch) =====
// blocks [0,5000)=branch0, [5000,10000)=branch1, ... -> concurrent blocks share one
// 5.1 MB Pn slice (L2-resident gathers). 2-deep sn/ef pipe, 1-deep 16B bf16 gather.
__global__ __launch_bounds__(256) void k_fused(
    const unsigned short* __restrict__ HPh, // [N,768] bf16: hv | Pn
    const float* __restrict__ EFC,          // CSR-ordered edge feats [E,12]
    const float* __restrict__ pw0, const float* __restrict__ pw1, const float* __restrict__ pw2,
    const float* __restrict__ v0, const float* __restrict__ v1, const float* __restrict__ v2,
    const float* __restrict__ b20, const float* __restrict__ b21, const float* __restrict__ b22,
    const int* __restrict__ csr_src,
    const int* __restrict__ offs, const int* __restrict__ cnt,
    unsigned short* __restrict__ AXh)       // [N,384] bf16 out
{
    const int k = blockIdx.x / (NN / 4);
    const int n = (blockIdx.x - k * (NN / 4)) * 4 + (threadIdx.x >> 6);
    const int lane = threadIdx.x & 63;
    const int er = lane >> 4, cg = lane & 15;
    const int c8 = cg * 8;
    const float* pw = (k == 0) ? pw0 : (k == 1) ? pw1 : pw2;
    const float* vv = (k == 0) ? v0 : (k == 1) ? v1 : v2;
    const float b2 = ((k == 0) ? b20 : (k == 1) ? b21 : b22)[0];
    const float* We = pw + NFD * 128;

    const int o0 = offs[n];
    const int deg = cnt[n];
    unsigned short* arow = AXh + (size_t)n * 384 + k * 128 + c8;
    if (deg == 0) {
        if (er == 0) {
            us8v z;
#pragma unroll
            for (int i = 0; i < 8; i++) z[i] = 0;
            *(us8v*)arow = z;
        }
        return;
    }

    float4 wb0 = *(const float4*)(vv + 128 + c8);
    float4 wb1 = *(const float4*)(vv + 128 + c8 + 4);

    // qa = hv_k[n] . w2a   (hv in bf16)
    float qa;
    {
        float4 wa0 = *(const float4*)(vv + c8);
        float4 wa1 = *(const float4*)(vv + c8 + 4);
        us8v h8 = *(const us8v*)(HPh + (size_t)n * 768 + k * 128 + c8);
        qa = b2f(h8[0]) * wa0.x + b2f(h8[1]) * wa0.y + b2f(h8[2]) * wa0.z + b2f(h8[3]) * wa0.w
           + b2f(h8[4]) * wa1.x + b2f(h8[5]) * wa1.y + b2f(h8[6]) * wa1.z + b2f(h8[7]) * wa1.w;
#pragma unroll
        for (int d = 1; d < 16; d <<= 1) qa += __shfl_xor(qa, d, 64);
    }

    const unsigned short* PHk = HPh + 384 + (size_t)k * 128 + c8;

    // prologue: stage 0 and stage 1 indices/features, stage-0 gather
    int q0 = o0 + ((er < deg) ? er : (deg - 1));
    int sn0 = csr_src[q0];
    const float4* ep0 = (const float4*)(EFC + (size_t)q0 * 12);
    float4 e00 = ep0[0], e01 = ep0[1], e02 = ep0[2];
    int sn1 = sn0;
    float4 e10 = e00, e11 = e01, e12 = e02;
    if (deg > 4) {
        int p1 = 4 + er;
        int q1 = o0 + ((p1 < deg) ? p1 : (deg - 1));
        sn1 = csr_src[q1];
        const float4* ep1 = (const float4*)(EFC + (size_t)q1 * 12);
        e10 = ep1[0]; e11 = ep1[1]; e12 = ep1[2];
    }
    us8v px0 = *(const us8v*)(PHk + (size_t)sn0 * 768);

    float4 a0 = make_float4(0.f, 0.f, 0.f, 0.f);
    float4 a1 = make_float4(0.f, 0.f, 0.f, 0.f);
    float s = 0.f;

    for (int base = 0; base < deg; base += 4) {
        const bool on = (base + er) < deg;
        us8v px1 = px0;
        if (base + 4 < deg) px1 = *(const us8v*)(PHk + (size_t)sn1 * 768);
        int sn2 = sn1;
        float4 e20 = e10, e21 = e11, e22 = e12;
        if (base + 8 < deg) {
            int p2 = base + 8 + er;
            int q2 = o0 + ((p2 < deg) ? p2 : (deg - 1));
            sn2 = csr_src[q2];
            const float4* ep2 = (const float4*)(EFC + (size_t)q2 * 12);
            e20 = ep2[0]; e21 = ep2[1]; e22 = ep2[2];
        }
        float ef[12] = {e00.x, e00.y, e00.z, e00.w, e01.x, e01.y, e01.z, e01.w,
                        e02.x, e02.y, e02.z, e02.w};
        float4 x0 = make_float4(0.f, 0.f, 0.f, 0.f);
        float4 x1 = make_float4(0.f, 0.f, 0.f, 0.f);
#pragma unroll
        for (int j = 0; j < 12; j++) {
            float e = ef[j];
            float4 w0 = *(const float4*)(We + j * 128 + c8);
            float4 w1 = *(const float4*)(We + j * 128 + c8 + 4);
            x0.x += e * w0.x; x0.y += e * w0.y; x0.z += e * w0.z; x0.w += e * w0.w;
            x1.x += e * w1.x; x1.y += e * w1.y; x1.z += e * w1.z; x1.w += e * w1.w;
        }
        x0.x = leakyf(x0.x + b2f(px0[0])); x0.y = leakyf(x0.y + b2f(px0[1]));
        x0.z = leakyf(x0.z + b2f(px0[2])); x0.w = leakyf(x0.w + b2f(px0[3]));
        x1.x = leakyf(x1.x + b2f(px0[4])); x1.y = leakyf(x1.y + b2f(px0[5]));
        x1.z = leakyf(x1.z + b2f(px0[6])); x1.w = leakyf(x1.w + b2f(px0[7]));
        float dd = x0.x * wb0.x + x0.y * wb0.y + x0.z * wb0.z + x0.w * wb0.w
                 + x1.x * wb1.x + x1.y * wb1.y + x1.z * wb1.z + x1.w * wb1.w;
#pragma unroll
        for (int d = 1; d < 16; d <<= 1) dd += __shfl_xor(dd, d, 64);
        float ex = on ? __expf(leakyf(qa + dd + b2)) : 0.f;
        a0.x += ex * x0.x; a0.y += ex * x0.y; a0.z += ex * x0.z; a0.w += ex * x0.w;
        a1.x += ex * x1.x; a1.y += ex * x1.y; a1.z += ex * x1.z; a1.w += ex * x1.w;
        s += ex;
        px0 = px1; sn1 = sn2;
        e00 = e10; e01 = e11; e02 = e12;
        e10 = e20; e11 = e21; e12 = e22;
    }
#pragma unroll
    for (int d = 16; d < 64; d <<= 1) {
        a0.x += __shfl_xor(a0.x, d, 64); a0.y += __shfl_xor(a0.y, d, 64);
        a0.z += __shfl_xor(a0.z, d, 64); a0.w += __shfl_xor(a0.w, d, 64);
        a1.x += __shfl_xor(a1.x, d, 64); a1.y += __shfl_xor(a1.y, d, 64);
        a1.z += __shfl_xor(a1.z, d, 64); a1.w += __shfl_xor(a1.w, d, 64);
        s += __shfl_xor(s, d, 64);
    }
    if (er == 0) {
        float inv = 1.f / s;
        us8v outv;
        outv[0] = f2b(a0.x * inv); outv[1] = f2b(a0.y * inv);
        outv[2] = f2b(a0.z * inv); outv[3] = f2b(a0.w * inv);
        outv[4] = f2b(a1.x * inv); outv[5] = f2b(a1.y * inv);
        outv[6] = f2b(a1.z * inv); outv[7] = f2b(a1.w * inv);
        *(us8v*)arow = outv;
    }
}

// ================= fused GRU gates + relu =================
__global__ void k_gru2(const float* __restrict__ G, const float* __restrict__ X,
                       const float* __restrict__ bih, const float* __restrict__ bhh,
                       float* __restrict__ out)
{
    int idx = blockIdx.x * 256 + threadIdx.x;
    if (idx >= NN * 128) return;
    int n = idx >> 7, c = idx & 127;
    const float* g = G + (size_t)n * 512;
    float r = 1.f / (1.f + __expf(-(g[c] + bih[c] + bhh[c])));
    float z = 1.f / (1.f + __expf(-(g[128 + c] + bih[128 + c] + bhh[128 + c])));
    float nv = tanhf(g[256 + c] + bih[256 + c] + r * (g[384 + c] + bhh[256 + c]));
    float h = X[(size_t)n * 256 + 128 + c];
    float v = (1.f - z) * nv + z * h;
    out[idx] = v > 0.f ? v : 0.f;
}

extern "C" void kernel_launch(void* const* d_in, const int* in_sizes, int n_in,
                              void* d_out, int out_size, void* d_ws, size_t ws_size,
                              hipStream_t stream)
{
    const float* nf = (const float*)d_in[0];
    const float* ef = (const float*)d_in[1];
    const float *pn_w[3], *pn_b[3], *pe1_w[3], *pe1_b[3], *pe2_w[3], *pe2_b[3], *et_w[3], *et_b[3];
    for (int k = 0; k < 3; k++) {
        int b = 2 + k * 8;
        pn_w[k] = (const float*)d_in[b + 0]; pn_b[k] = (const float*)d_in[b + 1];
        pe1_w[k] = (const float*)d_in[b + 2]; pe1_b[k] = (const float*)d_in[b + 3];
        pe2_w[k] = (const float*)d_in[b + 4]; pe2_b[k] = (const float*)d_in[b + 5];
        et_w[k] = (const float*)d_in[b + 6]; et_b[k] = (const float*)d_in[b + 7];
    }
    const float* mca_w = (const float*)d_in[26]; const float* mca_b = (const float*)d_in[27];
    const float* mcn_w = (const float*)d_in[28]; const float* mcn_b = (const float*)d_in[29];
    const float* wih = (const float*)d_in[30]; const float* whh = (const float*)d_in[31];
    const float* bih = (const float*)d_in[32]; const float* bhh = (const float*)d_in[33];
    const int* src = (const int*)d_in[34];
    const int* dst = (const int*)d_in[35];

    float* W = (float*)d_ws;
    size_t o = 0;
    float* Xb = W + o;                                  o += (size_t)NN * 256;  // fp32 [N,256]
    unsigned short* HPh = (unsigned short*)(W + o);     o += (size_t)NN * 384;  // bf16 [N,768]
    unsigned short* Xh  = (unsigned short*)(W + o);     o += (size_t)NN * 128;  // bf16 [N,256]
    unsigned short* PKt = (unsigned short*)(W + o);     o += SZ_PKT / 2;
    unsigned short* WGt = (unsigned short*)(W + o);     o += SZ_WGT / 2;
    unsigned short* ETt = (unsigned short*)(W + o);     o += SZ_ETT / 2;
    unsigned short* MCt = (unsigned short*)(W + o);     o += SZ_MCT / 2;
    float* PB = W + o;                                  o += 768;
    float* Z512 = W + o;                                o += 512;
    int* cnt = (int*)(W + o);
    int* total = cnt + NN;
    int* offs = total + 1;
    int* cur = offs + NN;
    int* csr_src = cur + NN;                            o += (size_t)3 * NN + 1 + EE;
    // G-region: G fp32 [N,512] overlays AXh + EFC (+slack); PA overlays EFC head.
    float* G = W + o;
    unsigned short* AXh = (unsigned short*)G;           // bf16 [N,384] = NN*192 floats
    float* EFC = G + (size_t)NN * 192;                  // fp32 [E,12]
    unsigned short* PA = (unsigned short*)EFC;          // bf16 [N,80] (dead before k_fill)
    size_t gspan = (size_t)NN * 512;                    // 10.24M floats
    size_t espan = (size_t)NN * 192 + (size_t)EE * 12;  // 7.68M floats
    o += (gspan > espan) ? gspan : espan;
    size_t need = o * 4;
    if (ws_size < need) return;  // fail loudly (out stays poisoned)

    hipMemsetAsync(cnt, 0, (NN + 1) * sizeof(int), stream);  // cnt + total

    dim3 blk(256);
    k_pack<<<(SZ_PKT + SZ_WGT + SZ_ETT + SZ_MCT + 768 + 512 + 255) / 256, blk, 0, stream>>>(
        pn_w[0], pn_w[1], pn_w[2], pn_b[0], pn_b[1], pn_b[2],
        pe1_w[0], pe1_w[1], pe1_w[2], pe1_b[0], pe1_b[1], pe1_b[2],
        wih, whh, et_w[0], et_w[1], et_w[2], mca_w, mcn_w,
        PKt, WGt, ETt, MCt, PB, Z512);
    k_prep<<<(NN * 80 + 255) / 256, blk, 0, stream>>>(nf, PA);

    const int rt = (NN + 127) / 128;   // 157

    // HPh = bf16[ leaky(PA@pnw+b) | PA@pe1w+b ]
    {
        GJob j = {PA, PKt, PB, nullptr, HPh, nullptr, 80, 0, 0, 768, 0};
        gemm_bf<3><<<dim3(rt * 6, 1), blk, 0, stream>>>(j, j, j, NN, 80, 768, 384);
    }

    k_count<<<(EE + 255) / 256, blk, 0, stream>>>(dst, cnt);
    k_off<<<(NN + 255) / 256, blk, 0, stream>>>(cnt, offs, cur, total);
    k_fill<<<(EE + 255) / 256, blk, 0, stream>>>(dst, src, ef, cur, csr_src, EFC);

    // fused: qa + he1k + logits + softmax + weighted aggregation (branch-major)
    k_fused<<<dim3((NN / 4) * 3), blk, 0, stream>>>(HPh, EFC,
        pe1_w[0], pe1_w[1], pe1_w[2], pe2_w[0], pe2_w[1], pe2_w[2],
        pe2_b[0], pe2_b[1], pe2_b[2], csr_src, offs, cnt, AXh);

    // ctx_k = elu(AXh_k @ et_w + b) -> HPh cols 384.. (bf16, batched over k)
    {
        GJob j0 = {AXh, ETt,             et_b[0], nullptr, HPh, cnt, 384, 0,   0, 768, 384};
        GJob j1 = {AXh, ETt + 16384,     et_b[1], nullptr, HPh, cnt, 384, 128, 0, 768, 512};
        GJob j2 = {AXh, ETt + 32768,     et_b[2], nullptr, HPh, cnt, 384, 256, 0, 768, 640};
        gemm_bf<2><<<dim3(rt, 3), blk, 0, stream>>>(j0, j1, j2, NN, 128, 128, 0);
    }
    // Xb/Xh[:,0:128] = ctx@mca_w+b ; [:,128:256] = hv@mcn_w+b
    {
        GJob j0 = {HPh, MCt,         mca_b, Xb, Xh, nullptr, 768, 384, 256, 256, 0};
        GJob j1 = {HPh, MCt + 49152, mcn_b, Xb, Xh, nullptr, 768, 0,   256, 256, 128};
        gemm_bf<0><<<dim3(rt, 2), blk, 0, stream>>>(j0, j1, j1, NN, 384, 128, 0);
    }
    // G = Xh @ WGt  (r|z|in|hn)
    {
        GJob j = {Xh, WGt, Z512, G, nullptr, nullptr, 256, 0, 512, 0, 0};
        gemm_bf<0><<<dim3(rt * 4, 1), blk, 0, stream>>>(j, j, j, NN, 256, 512, 0);
    }

    k_gru2<<<(NN * 128 + 255) / 256, blk, 0, stream>>>(G, Xb, bih, bhh, (float*)d_out);
}